// Round 7
// baseline (804.546 us; speedup 1.0000x reference)
//
#include <hip/hip_runtime.h>

// ---------------------------------------------------------------------------
// 2-layer GCN: out = A_norm @ relu(A_norm @ (x@W1) + b1) @ W2 (+b2)
// A_norm = D^-1/2 (A+I) D^-1/2, factored: out[d] = dinv[d]*sum_src(g[src]) + b
// with g = dinv * (x @ W).
//
// R7: unfused baseline 519 us. R8-R10: chunked-gather exploration (see notes).
// R11: 64-channel chunks [2][N][64] bf16 = one full 128 B line per edge,
//      2 passes, sequential halves. agg 104 us each, FETCH 320 MB, 3.6 TB/s
//      miss path -> within ~30% of structural floor. Total 509 us.
// R12: aggregates kept; CSR build rewritten. The radix chain (hist/col_scan/
//      bucket_scan/partition/build, ~120-185 us) sorted srcs within rows --
//      but aggregation is an order-independent sum, only GROUPING is needed.
//      New: k_deg (3.3M atomicAdd on 400 KB L2-resident counters) ->
//      k_scanA/k_scanC (block-sum + offset scan; row_ptr, cur, dinv; wprep
//      folded into scanA's extra blocks) -> k_scatter (single full-span
//      scattered-write pass, atomic cursors). One scatter pass instead of
//      partition+build; 3 fewer streaming reads of edge data.
// ---------------------------------------------------------------------------

#define STILE 4096       // elements per scan block (256 threads x 16)

typedef unsigned short ushort_t;
typedef unsigned long long ull_t;
typedef __attribute__((ext_vector_type(8))) short short8;
typedef __attribute__((ext_vector_type(4))) float f32x4;

__device__ __forceinline__ unsigned short f32_to_bf16_rne(float x) {
    unsigned int v = __float_as_uint(x);
    unsigned int r = v + 0x7fffu + ((v >> 16) & 1u);
    return (unsigned short)(r >> 16);
}

// Degree histogram: items = E edges + N self-loops. deg pre-zeroed (memset).
__global__ __launch_bounds__(256) void k_deg(
    const int* __restrict__ dst, int* __restrict__ deg, int e, int total) {
    int stride = gridDim.x * 256;
    for (int i = blockIdx.x * 256 + threadIdx.x; i < total; i += stride) {
        int d = (i < e) ? dst[i] : (i - e);
        atomicAdd(&deg[d], 1);
    }
}

// Scan pass A: block sums of deg over STILE tiles (blocks < nsb).
// Blocks >= nsb: weight prep W (f32,[k][n]) -> Wp (bf16,[n][k]), 128 blocks.
__global__ __launch_bounds__(256) void k_scanA(
    const int* __restrict__ deg, int* __restrict__ bsums, int n, int nsb,
    const float* __restrict__ W1, const float* __restrict__ W2,
    ushort_t* __restrict__ Wp1, ushort_t* __restrict__ Wp2) {
    int b = blockIdx.x;
    int t = threadIdx.x;
    if (b >= nsb) {
        int idx = (b - nsb) * 256 + t;
        int which = idx >> 14;
        int e = idx & 16383;
        int nn = e & 127, k = e >> 7;
        const float* W = which ? W2 : W1;
        ushort_t* Wp = which ? Wp2 : Wp1;
        Wp[nn * 128 + k] = f32_to_bf16_rne(W[k * 128 + nn]);
        return;
    }
    __shared__ int sd[256];
    int base = b * STILE;
    int s = 0;
#pragma unroll
    for (int j = 0; j < 16; j++) {
        int i = base + j * 256 + t;
        if (i < n) s += deg[i];
    }
    sd[t] = s;
    __syncthreads();
    for (int off = 128; off > 0; off >>= 1) {
        if (t < off) sd[t] += sd[t + off];
        __syncthreads();
    }
    if (t == 0) bsums[b] = sd[0];
}

// Scan pass C: exclusive scan -> row_ptr + cur (scatter cursors) + dinv.
// nsb <= 256 required (N <= 1M).
__global__ __launch_bounds__(256) void k_scanC(
    const int* __restrict__ deg, const int* __restrict__ bsums,
    int* __restrict__ row_ptr, int* __restrict__ cur,
    float* __restrict__ dinv, int n, int total) {
    __shared__ int sd[256];
    int b = blockIdx.x, t = threadIdx.x;
    // block offset = sum of bsums[0..b)
    sd[t] = (t < b) ? bsums[t] : 0;
    __syncthreads();
    for (int off = 128; off > 0; off >>= 1) {
        if (t < off) sd[t] += sd[t + off];
        __syncthreads();
    }
    int boff = sd[0];
    __syncthreads();
    // thread t owns contiguous [base, base+16)
    int base = b * STILE + t * 16;
    int d[16];
    int ts = 0;
#pragma unroll
    for (int j = 0; j < 16; j++) {
        int i = base + j;
        d[j] = (i < n) ? deg[i] : 0;
        ts += d[j];
    }
    sd[t] = ts;
    __syncthreads();
    for (int off = 1; off < 256; off <<= 1) {
        int u = (t >= off) ? sd[t - off] : 0;
        __syncthreads();
        sd[t] += u;
        __syncthreads();
    }
    int run = boff + sd[t] - ts;   // exclusive prefix for this thread
#pragma unroll
    for (int j = 0; j < 16; j++) {
        int i = base + j;
        if (i < n) {
            row_ptr[i] = run;
            cur[i] = run;
            dinv[i] = rsqrtf((float)d[j]);   // deg >= 1 (self-loop)
            run += d[j];
        }
    }
    if (b == 0 && t == 0) row_ptr[n] = total;
}

// Scatter: group edges by dst via atomic cursors (order within row is
// irrelevant -- aggregation is an order-independent sum).
__global__ __launch_bounds__(256) void k_scatter(
    const int* __restrict__ src, const int* __restrict__ dst,
    int* __restrict__ cur, int* __restrict__ srcs, int e, int total) {
    int stride = gridDim.x * 256;
    for (int i = blockIdx.x * 256 + threadIdx.x; i < total; i += stride) {
        int s, d;
        if (i < e) { s = src[i]; d = dst[i]; }
        else       { s = i - e;  d = s; }
        int pos = atomicAdd(&cur[d], 1);
        srcs[pos] = s;
    }
}

// ---------------------------------------------------------------------------
// GEMM1: G[ch][r][64] = bf16( dinv[r] * (A @ W)[r][ch*64..] ), A: Mx128 f32.
// 64-channel-chunk-major output ([2][M][64] bf16). Split-A bf16 MFMA.
// mfma_f32_16x16x32_bf16 layouts (HW-verified, guide m89/m91):
//   A: lane holds A[m=lane&15][k=(lane>>4)*8 + j]
//   B: lane holds B[k=(lane>>4)*8 + j][n=lane&15]   (Wp is [n][k] bf16)
//   C/D: col=lane&15, row=(lane>>4)*4 + reg
// Channel c*16+m lives in chunk c>>2 at offset (c&3)*16 + m.
// ---------------------------------------------------------------------------
__global__ __launch_bounds__(256) void k_gemm1(
    const float* __restrict__ A, const ushort_t* __restrict__ Wp,
    const float* __restrict__ dinv, ushort_t* __restrict__ G, int M) {
    int t = threadIdx.x;
    int row0 = blockIdx.x * 64;
    int wv = t >> 6;
    int lane = t & 63;
    int m = lane & 15;
    int quad = lane >> 4;

    int gr_row = row0 + wv * 16 + m;
    int gcl = gr_row < M ? gr_row : M - 1;
    const float* ap = A + (size_t)gcl * 128 + quad * 8;

    f32x4 acc[8];
#pragma unroll
    for (int c = 0; c < 8; c++) acc[c] = (f32x4){0.f, 0.f, 0.f, 0.f};

#pragma unroll
    for (int ks = 0; ks < 4; ks++) {
        int kb = ks * 32 + quad * 8;
        float xs[8];
        *(float4*)&xs[0] = *(const float4*)(ap + ks * 32);
        *(float4*)&xs[4] = *(const float4*)(ap + ks * 32 + 4);
        short8 ahi, alo;
#pragma unroll
        for (int j = 0; j < 8; j++) {
            unsigned short h = f32_to_bf16_rne(xs[j]);
            ahi[j] = (short)h;
            float hf = __uint_as_float((unsigned int)h << 16);
            alo[j] = (short)f32_to_bf16_rne(xs[j] - hf);
        }
#pragma unroll
        for (int c = 0; c < 8; c++) {
            short8 b8 = *(const short8*)(Wp + (size_t)(c * 16 + m) * 128 + kb);
            acc[c] = __builtin_amdgcn_mfma_f32_16x16x32_bf16(ahi, b8, acc[c], 0, 0, 0);
            acc[c] = __builtin_amdgcn_mfma_f32_16x16x32_bf16(alo, b8, acc[c], 0, 0, 0);
        }
    }

    int rbase = row0 + wv * 16 + quad * 4;
#pragma unroll
    for (int reg = 0; reg < 4; reg++) {
        int gr = rbase + reg;
        if (gr < M) {
            float dv = dinv[gr];
#pragma unroll
            for (int c = 0; c < 8; c++)
                G[((size_t)(c >> 2) * M + gr) * 64 + (c & 3) * 16 + m] =
                    f32_to_bf16_rne(acc[c][reg] * dv);
        }
    }
}

// ---------------------------------------------------------------------------
// GEMM2: in-place actG2[ch][r][64] = bf16( dinv[r] * (act @ W2)[r][..] ).
// act rows are wave-private (block = 64 rows, wave = 16 rows); in a wave all
// A-loads complete (MFMA data dep) before epilogue stores -> in-place is safe.
// Clamped tail rows may read racing data but their results are discarded.
// NOTE: actG2 deliberately NOT __restrict__ (true aliasing).
// ---------------------------------------------------------------------------
__global__ __launch_bounds__(256) void k_gemm2(
    ushort_t* actG2, const ushort_t* __restrict__ Wp,
    const float* __restrict__ dinv, int M) {
    int t = threadIdx.x;
    int row0 = blockIdx.x * 64;
    int wv = t >> 6;
    int lane = t & 63;
    int m = lane & 15;
    int quad = lane >> 4;

    int gr_row = row0 + wv * 16 + m;
    int gcl = gr_row < M ? gr_row : M - 1;

    f32x4 acc[8];
#pragma unroll
    for (int c = 0; c < 8; c++) acc[c] = (f32x4){0.f, 0.f, 0.f, 0.f};

#pragma unroll
    for (int ks = 0; ks < 4; ks++) {
        int kb = ks * 32 + quad * 8;
        // chunked act: channels kb..kb+7 live in chunk kb>>6 at offset kb&63
        short8 a8 = *(const short8*)(actG2 + ((size_t)(kb >> 6) * M + gcl) * 64 + (kb & 63));
#pragma unroll
        for (int c = 0; c < 8; c++) {
            short8 b8 = *(const short8*)(Wp + (size_t)(c * 16 + m) * 128 + kb);
            acc[c] = __builtin_amdgcn_mfma_f32_16x16x32_bf16(a8, b8, acc[c], 0, 0, 0);
        }
    }

    int rbase = row0 + wv * 16 + quad * 4;
#pragma unroll
    for (int reg = 0; reg < 4; reg++) {
        int gr = rbase + reg;
        if (gr < M) {
            float dv = dinv[gr];
#pragma unroll
            for (int c = 0; c < 8; c++)
                actG2[((size_t)(c >> 2) * M + gr) * 64 + (c & 3) * 16 + m] =
                    f32_to_bf16_rne(acc[c][reg] * dv);
        }
    }
}

// ---------------------------------------------------------------------------
// R11 aggregates: 2 passes of 64 channels. Table per pass = N*128 B =
// 12.8 MB; each edge touches exactly ONE fully-used 128 B line (6.6M total
// line-touches = structural minimum). chunk = (bx >= half) sequential
// halves -> one table live at a time. Wave = 4 nodes x 16 lanes (8 B/lane).
// Serial exec-masked edge walk per 16-lane group, unroll-4 MLP.
// ---------------------------------------------------------------------------

#define ACC_U(u)                                     \
    do {                                             \
        unsigned int ul_ = (unsigned int)(u);        \
        unsigned int uh_ = (unsigned int)((u) >> 32);\
        a0 += __uint_as_float(ul_ << 16);            \
        a1 += __uint_as_float(ul_ & 0xffff0000u);    \
        a2 += __uint_as_float(uh_ << 16);            \
        a3 += __uint_as_float(uh_ & 0xffff0000u);    \
    } while (0)

// Aggregate 1: act[chunk][node][64] = bf16(relu(dinv*sum(G1[src]) + b1)).
__global__ __launch_bounds__(256) void k_agg1(
    const int* __restrict__ row_ptr, const int* __restrict__ srcs,
    const ushort_t* __restrict__ G, const float* __restrict__ dinv,
    const float* __restrict__ bias, ull_t* __restrict__ ActOut,
    int n, int half) {
    int bx = blockIdx.x;
    int chunk = bx >= half ? 1 : 0;
    int tile = bx - chunk * half;
    int t = threadIdx.x;
    int lane = t & 63;
    int g = lane >> 4;     // node sub-index within wave (0..3)
    int q = lane & 15;     // 8 B quad within 64 channels
    int node = tile * 16 + (t >> 6) * 4 + g;
    bool valid = node < n;
    int nc = valid ? node : n - 1;
    int beg = row_ptr[nc], end = row_ptr[nc + 1];
    const ull_t* Tq = (const ull_t*)G + (size_t)chunk * n * 16 + q;
    float a0 = 0.f, a1 = 0.f, a2 = 0.f, a3 = 0.f;
    int e = beg;
    for (; e + 4 <= end; e += 4) {
        int s0 = srcs[e], s1 = srcs[e + 1], s2 = srcs[e + 2], s3 = srcs[e + 3];
        ull_t u0 = Tq[(size_t)s0 * 16];
        ull_t u1 = Tq[(size_t)s1 * 16];
        ull_t u2 = Tq[(size_t)s2 * 16];
        ull_t u3 = Tq[(size_t)s3 * 16];
        ACC_U(u0); ACC_U(u1); ACC_U(u2); ACC_U(u3);
    }
    for (; e < end; ++e) {
        int s = srcs[e];
        ull_t u = Tq[(size_t)s * 16];
        ACC_U(u);
    }
    if (valid) {
        float dv = dinv[node];
        const float* bp = bias + chunk * 64 + q * 4;
        a0 = fmaxf(fmaf(a0, dv, bp[0]), 0.f);
        a1 = fmaxf(fmaf(a1, dv, bp[1]), 0.f);
        a2 = fmaxf(fmaf(a2, dv, bp[2]), 0.f);
        a3 = fmaxf(fmaf(a3, dv, bp[3]), 0.f);
        unsigned int p0 = (unsigned int)f32_to_bf16_rne(a0) |
                          ((unsigned int)f32_to_bf16_rne(a1) << 16);
        unsigned int p1 = (unsigned int)f32_to_bf16_rne(a2) |
                          ((unsigned int)f32_to_bf16_rne(a3) << 16);
        ull_t uo = (ull_t)p0 | ((ull_t)p1 << 32);
        __builtin_nontemporal_store(uo, ActOut + ((size_t)chunk * n + node) * 16 + q);
    }
}

// Aggregate 2: out[node][chunk*64..] = dinv*sum(G2[src]) + b2 (f32, nt store).
__global__ __launch_bounds__(256) void k_agg2(
    const int* __restrict__ row_ptr, const int* __restrict__ srcs,
    const ushort_t* __restrict__ G, const float* __restrict__ dinv,
    const float* __restrict__ bias, float* __restrict__ Out,
    int n, int half) {
    int bx = blockIdx.x;
    int chunk = bx >= half ? 1 : 0;
    int tile = bx - chunk * half;
    int t = threadIdx.x;
    int lane = t & 63;
    int g = lane >> 4;
    int q = lane & 15;
    int node = tile * 16 + (t >> 6) * 4 + g;
    bool valid = node < n;
    int nc = valid ? node : n - 1;
    int beg = row_ptr[nc], end = row_ptr[nc + 1];
    const ull_t* Tq = (const ull_t*)G + (size_t)chunk * n * 16 + q;
    float a0 = 0.f, a1 = 0.f, a2 = 0.f, a3 = 0.f;
    int e = beg;
    for (; e + 4 <= end; e += 4) {
        int s0 = srcs[e], s1 = srcs[e + 1], s2 = srcs[e + 2], s3 = srcs[e + 3];
        ull_t u0 = Tq[(size_t)s0 * 16];
        ull_t u1 = Tq[(size_t)s1 * 16];
        ull_t u2 = Tq[(size_t)s2 * 16];
        ull_t u3 = Tq[(size_t)s3 * 16];
        ACC_U(u0); ACC_U(u1); ACC_U(u2); ACC_U(u3);
    }
    for (; e < end; ++e) {
        int s = srcs[e];
        ull_t u = Tq[(size_t)s * 16];
        ACC_U(u);
    }
    if (valid) {
        float dv = dinv[node];
        const float* bp = bias + chunk * 64 + q * 4;
        f32x4 o;
        o.x = fmaf(a0, dv, bp[0]);
        o.y = fmaf(a1, dv, bp[1]);
        o.z = fmaf(a2, dv, bp[2]);
        o.w = fmaf(a3, dv, bp[3]);
        __builtin_nontemporal_store(o,
            (f32x4*)(Out + (size_t)node * 128 + chunk * 64 + q * 4));
    }
}

extern "C" void kernel_launch(void* const* d_in, const int* in_sizes, int n_in,
                              void* d_out, int out_size, void* d_ws, size_t ws_size,
                              hipStream_t stream) {
    const float* x  = (const float*)d_in[0];
    const int*   ei = (const int*)d_in[1];
    const float* W1 = (const float*)d_in[2];
    const float* b1 = (const float*)d_in[3];
    const float* W2 = (const float*)d_in[4];
    const float* b2 = (const float*)d_in[5];
    float* out = (float*)d_out;

    const int C = 128;
    const int N = in_sizes[0] / C;
    const int E = in_sizes[1] / 2;
    const int* src = ei;
    const int* dst = ei + E;
    const int total = E + N;
    const int nsb = (N + STILE - 1) / STILE;   // scan blocks (25 for 100k)

    char* ws = (char*)d_ws;
    size_t off = 0;
    auto alloc = [&](size_t bytes) -> void* {
        void* p = ws + off;
        off = (off + bytes + 511) & ~(size_t)511;
        return p;
    };
    int*   deg     = (int*)alloc((size_t)N * 4);
    int*   bsums   = (int*)alloc(256 * 4);
    int*   row_ptr = (int*)alloc(((size_t)N + 1) * 4);
    int*   cur     = (int*)alloc((size_t)N * 4);
    float* dinv    = (float*)alloc((size_t)N * 4);
    int*   srcs    = (int*)alloc((size_t)total * 4);
    ushort_t* Wp1  = (ushort_t*)alloc(128 * 128 * 2);
    ushort_t* Wp2  = (ushort_t*)alloc(128 * 128 * 2);
    ushort_t* G1   = (ushort_t*)alloc((size_t)N * C * 2);
    ushort_t* actG2 = (ushort_t*)alloc((size_t)N * C * 2);

    // ---- atomic-cursor CSR build (grouping only; no sort needed) ----
    hipMemsetAsync(deg, 0, (size_t)N * 4, stream);
    k_deg<<<2048, 256, 0, stream>>>(dst, deg, E, total);
    k_scanA<<<nsb + 128, 256, 0, stream>>>(deg, bsums, N, nsb, W1, W2, Wp1, Wp2);
    k_scanC<<<nsb, 256, 0, stream>>>(deg, bsums, row_ptr, cur, dinv, N, total);
    k_scatter<<<2048, 256, 0, stream>>>(src, dst, cur, srcs, E, total);

    // agg grid: two sequential halves (chunk = bx >= half), 16 nodes/block
    const int half = (N + 15) / 16;
    dim3 agrid(half * 2);

    // ---- layer 1: G1[ch][r][64] = bf16(dinv*(x@W1)); act chunked bf16 ----
    k_gemm1<<<(N + 63) / 64, 256, 0, stream>>>(x, Wp1, dinv, G1, N);
    k_agg1<<<agrid, 256, 0, stream>>>(row_ptr, srcs, G1, dinv, b1,
                                      (ull_t*)actG2, N, half);

    // ---- layer 2: G2 = bf16(dinv*(act@W2)) in-place chunked; out ----
    k_gemm2<<<(N + 63) / 64, 256, 0, stream>>>(actG2, Wp2, dinv, N);
    k_agg2<<<agrid, 256, 0, stream>>>(row_ptr, srcs, actG2, dinv, b2, out, N, half);
}

// Round 8
// 495.815 us; speedup vs baseline: 1.6227x; 1.6227x over previous
//
#include <hip/hip_runtime.h>

// ---------------------------------------------------------------------------
// 2-layer GCN: out = A_norm @ relu(A_norm @ (x@W1) + b1) @ W2 (+b2)
// A_norm = D^-1/2 (A+I) D^-1/2, factored: out[d] = dinv[d]*sum_src(g[src]) + b
// with g = dinv * (x @ W).
//
// R7: unfused 519. R11: 64-ch chunk aggregates (104 us each), total 509.
// R12: FAILED single-pass atomic scatter (276-305 us, VALUBusy 0.3%):
//      random 4 B stores dirty whole 64 B sectors (WRITE 198 MB) and the
//      atomic-return -> dependent-store chain is latency-bound. Lesson:
//      scattered writes must be bucket-localized.
// R13: aggs/gemms = R11 verbatim. CSR chain: 5 kernels -> 3.
//      k_part2: per-block two-phase (LDS count -> global atomicAdd reserves
//      contiguous span in pairs[b*CAP..] -> LDS-cursor scatter). Keeps R11
//      partition's ~21-consecutive write locality, deletes Cmat machinery
//      (hist_tiles + col_scan + 2 dispatches). Within-bucket order is
//      nondeterministic -- sums are order-independent.
//      k_bscan: 782-entry scan -> bucket_ptr (+wprep in extra blocks).
//      k_build: R11's, reading pairs[b*CAP..b*CAP+cnt[b]).
// Requires N <= 131072 (17-bit src in packed pairs).
// ---------------------------------------------------------------------------

#define NPB 128          // nodes per bucket (dst >> 7)
#define NBMAX 1024       // supports N <= 131072
#define EPT 64           // edges per thread in partition kernel
#define PART_TILE (256 * EPT)
#define CAP 5120         // per-bucket pairs capacity (mean 4224 + 13 sigma)

typedef unsigned short ushort_t;
typedef unsigned long long ull_t;
typedef __attribute__((ext_vector_type(8))) short short8;
typedef __attribute__((ext_vector_type(4))) float f32x4;

__device__ __forceinline__ unsigned short f32_to_bf16_rne(float x) {
    unsigned int v = __float_as_uint(x);
    unsigned int r = v + 0x7fffu + ((v >> 16) & 1u);
    return (unsigned short)(r >> 16);
}

// Two-phase dynamic partition. cnt (global, pre-zeroed) accumulates bucket
// sizes; each block reserves contiguous spans per bucket -> write locality.
__global__ __launch_bounds__(256) void k_part2(
    const int* __restrict__ src, const int* __restrict__ dst,
    int* __restrict__ cnt, unsigned int* __restrict__ pairs,
    int e, int nbp, int total) {
    __shared__ int lcnt[NBMAX];
    __shared__ int lbase[NBMAX];
    int t = threadIdx.x;
    int t0 = blockIdx.x * PART_TILE;
    for (int k = t; k < nbp; k += 256) lcnt[k] = 0;
    __syncthreads();
    // phase 1: count this tile's edges per bucket (read dst)
#pragma unroll 4
    for (int j = 0; j < EPT; j++) {
        int i = t0 + j * 256 + t;
        if (i < total) {
            int d = (i < e) ? dst[i] : (i - e);
            atomicAdd(&lcnt[d >> 7], 1);
        }
    }
    __syncthreads();
    // phase 2: reserve contiguous spans in each bucket's region
    for (int k = t; k < nbp; k += 256) {
        int c = lcnt[k];
        lbase[k] = c ? atomicAdd(&cnt[k], c) : 0;
        lcnt[k] = 0;   // reuse as local cursor
    }
    __syncthreads();
    // phase 3: scatter (re-read src/dst; dst tile is L2-hot)
#pragma unroll 4
    for (int j = 0; j < EPT; j++) {
        int i = t0 + j * 256 + t;
        if (i < total) {
            int s, d;
            if (i < e) { s = src[i]; d = dst[i]; }
            else       { s = i - e;  d = s; }
            int b = d >> 7;
            int off = atomicAdd(&lcnt[b], 1) + lbase[b];
            pairs[(size_t)b * CAP + off] =
                (unsigned int)s | ((unsigned int)(d & 127) << 17);
        }
    }
}

// Exclusive scan of cnt -> bucket_ptr (block 0, nbp <= 1024); blocks 1..128
// do weight prep W (f32,[k][n]) -> Wp (bf16,[n][k]) for both layers.
__global__ __launch_bounds__(256) void k_bscan(
    const int* __restrict__ cnt, int* __restrict__ bucket_ptr,
    int nbp, int total,
    const float* __restrict__ W1, const float* __restrict__ W2,
    ushort_t* __restrict__ Wp1, ushort_t* __restrict__ Wp2) {
    if (blockIdx.x > 0) {
        int idx = (blockIdx.x - 1) * 256 + threadIdx.x;
        int which = idx >> 14;
        int e = idx & 16383;
        int n = e & 127, k = e >> 7;
        const float* W = which ? W2 : W1;
        ushort_t* Wp = which ? Wp2 : Wp1;
        Wp[n * 128 + k] = f32_to_bf16_rne(W[k * 128 + n]);
        return;
    }
    __shared__ int sd[256];
    int t = threadIdx.x;
    int c[4];
#pragma unroll
    for (int j = 0; j < 4; j++) {
        int k = t * 4 + j;
        c[j] = (k < nbp) ? cnt[k] : 0;
    }
    int s = c[0] + c[1] + c[2] + c[3];
    sd[t] = s;
    __syncthreads();
    for (int off = 1; off < 256; off <<= 1) {
        int v = (t >= off) ? sd[t - off] : 0;
        __syncthreads();
        sd[t] += v;
        __syncthreads();
    }
    int pre = sd[t] - s;
#pragma unroll
    for (int j = 0; j < 4; j++) {
        int k = t * 4 + j;
        if (k < nbp) bucket_ptr[k] = pre;
        pre += c[j];
    }
    if (t == 255) bucket_ptr[nbp] = total;
}

// One WG per bucket; LDS counts/scan -> row_ptr/dinv, fine-scatter to srcs.
__global__ __launch_bounds__(256) void k_build(
    const unsigned int* __restrict__ pairs, const int* __restrict__ cntg,
    const int* __restrict__ bucket_ptr,
    int* __restrict__ row_ptr, int* __restrict__ srcs,
    float* __restrict__ dinv, int n) {
    __shared__ int cnt[NPB];
    __shared__ int scn[NPB];
    __shared__ int cur[NPB];
    int b = blockIdx.x;
    int t = threadIdx.x;
    int node0 = b << 7;
    int cb = cntg[b];                       // pairs in this bucket
    int p0 = bucket_ptr[b];                 // srcs output base
    const unsigned int* bp = pairs + (size_t)b * CAP;
    if (t < NPB) cnt[t] = 0;
    __syncthreads();
    for (int i = t; i < cb; i += 256) {
        int dlow = (int)(bp[i] >> 17) & 127;
        atomicAdd(&cnt[dlow], 1);
    }
    __syncthreads();
    if (t < NPB) scn[t] = cnt[t];
    __syncthreads();
    for (int off = 1; off < NPB; off <<= 1) {
        int v = (t < NPB && t >= off) ? scn[t - off] : 0;
        __syncthreads();
        if (t < NPB) scn[t] += v;
        __syncthreads();
    }
    if (t < NPB) {
        int incl = scn[t];
        int excl = incl - cnt[t];
        int start = p0 + excl;
        cur[t] = start;
        int node = node0 + t;
        if (node < n) {
            row_ptr[node] = start;
            dinv[node] = rsqrtf((float)cnt[t]);  // deg >= 1 (self-loop)
            if (node == n - 1) row_ptr[n] = p0 + incl;
        }
    }
    __syncthreads();
    for (int i = t; i < cb; i += 256) {
        unsigned int pr = bp[i];
        int pos = atomicAdd(&cur[(pr >> 17) & 127], 1);
        srcs[pos] = (int)(pr & 0x1FFFFu);
    }
}

// ---------------------------------------------------------------------------
// GEMM1: G[ch][r][64] = bf16( dinv[r] * (A @ W)[r][ch*64..] ), A: Mx128 f32.
// 64-channel-chunk-major output ([2][M][64] bf16). Split-A bf16 MFMA.
// mfma_f32_16x16x32_bf16 layouts (HW-verified, guide m89/m91):
//   A: lane holds A[m=lane&15][k=(lane>>4)*8 + j]
//   B: lane holds B[k=(lane>>4)*8 + j][n=lane&15]   (Wp is [n][k] bf16)
//   C/D: col=lane&15, row=(lane>>4)*4 + reg
// Channel c*16+m lives in chunk c>>2 at offset (c&3)*16 + m.
// ---------------------------------------------------------------------------
__global__ __launch_bounds__(256) void k_gemm1(
    const float* __restrict__ A, const ushort_t* __restrict__ Wp,
    const float* __restrict__ dinv, ushort_t* __restrict__ G, int M) {
    int t = threadIdx.x;
    int row0 = blockIdx.x * 64;
    int wv = t >> 6;
    int lane = t & 63;
    int m = lane & 15;
    int quad = lane >> 4;

    int gr_row = row0 + wv * 16 + m;
    int gcl = gr_row < M ? gr_row : M - 1;
    const float* ap = A + (size_t)gcl * 128 + quad * 8;

    f32x4 acc[8];
#pragma unroll
    for (int c = 0; c < 8; c++) acc[c] = (f32x4){0.f, 0.f, 0.f, 0.f};

#pragma unroll
    for (int ks = 0; ks < 4; ks++) {
        int kb = ks * 32 + quad * 8;
        float xs[8];
        *(float4*)&xs[0] = *(const float4*)(ap + ks * 32);
        *(float4*)&xs[4] = *(const float4*)(ap + ks * 32 + 4);
        short8 ahi, alo;
#pragma unroll
        for (int j = 0; j < 8; j++) {
            unsigned short h = f32_to_bf16_rne(xs[j]);
            ahi[j] = (short)h;
            float hf = __uint_as_float((unsigned int)h << 16);
            alo[j] = (short)f32_to_bf16_rne(xs[j] - hf);
        }
#pragma unroll
        for (int c = 0; c < 8; c++) {
            short8 b8 = *(const short8*)(Wp + (size_t)(c * 16 + m) * 128 + kb);
            acc[c] = __builtin_amdgcn_mfma_f32_16x16x32_bf16(ahi, b8, acc[c], 0, 0, 0);
            acc[c] = __builtin_amdgcn_mfma_f32_16x16x32_bf16(alo, b8, acc[c], 0, 0, 0);
        }
    }

    int rbase = row0 + wv * 16 + quad * 4;
#pragma unroll
    for (int reg = 0; reg < 4; reg++) {
        int gr = rbase + reg;
        if (gr < M) {
            float dv = dinv[gr];
#pragma unroll
            for (int c = 0; c < 8; c++)
                G[((size_t)(c >> 2) * M + gr) * 64 + (c & 3) * 16 + m] =
                    f32_to_bf16_rne(acc[c][reg] * dv);
        }
    }
}

// ---------------------------------------------------------------------------
// GEMM2: in-place actG2[ch][r][64] = bf16( dinv[r] * (act @ W2)[r][..] ).
// act rows are wave-private (block = 64 rows, wave = 16 rows); in a wave all
// A-loads complete (MFMA data dep) before epilogue stores -> in-place is safe.
// Clamped tail rows may read racing data but their results are discarded.
// NOTE: actG2 deliberately NOT __restrict__ (true aliasing).
// ---------------------------------------------------------------------------
__global__ __launch_bounds__(256) void k_gemm2(
    ushort_t* actG2, const ushort_t* __restrict__ Wp,
    const float* __restrict__ dinv, int M) {
    int t = threadIdx.x;
    int row0 = blockIdx.x * 64;
    int wv = t >> 6;
    int lane = t & 63;
    int m = lane & 15;
    int quad = lane >> 4;

    int gr_row = row0 + wv * 16 + m;
    int gcl = gr_row < M ? gr_row : M - 1;

    f32x4 acc[8];
#pragma unroll
    for (int c = 0; c < 8; c++) acc[c] = (f32x4){0.f, 0.f, 0.f, 0.f};

#pragma unroll
    for (int ks = 0; ks < 4; ks++) {
        int kb = ks * 32 + quad * 8;
        // chunked act: channels kb..kb+7 live in chunk kb>>6 at offset kb&63
        short8 a8 = *(const short8*)(actG2 + ((size_t)(kb >> 6) * M + gcl) * 64 + (kb & 63));
#pragma unroll
        for (int c = 0; c < 8; c++) {
            short8 b8 = *(const short8*)(Wp + (size_t)(c * 16 + m) * 128 + kb);
            acc[c] = __builtin_amdgcn_mfma_f32_16x16x32_bf16(a8, b8, acc[c], 0, 0, 0);
        }
    }

    int rbase = row0 + wv * 16 + quad * 4;
#pragma unroll
    for (int reg = 0; reg < 4; reg++) {
        int gr = rbase + reg;
        if (gr < M) {
            float dv = dinv[gr];
#pragma unroll
            for (int c = 0; c < 8; c++)
                actG2[((size_t)(c >> 2) * M + gr) * 64 + (c & 3) * 16 + m] =
                    f32_to_bf16_rne(acc[c][reg] * dv);
        }
    }
}

// ---------------------------------------------------------------------------
// R11 aggregates: 2 passes of 64 channels. Table per pass = N*128 B =
// 12.8 MB; each edge touches exactly ONE fully-used 128 B line (6.6M total
// line-touches = structural minimum). chunk = (bx >= half) sequential
// halves -> one table live at a time. Wave = 4 nodes x 16 lanes (8 B/lane).
// Serial exec-masked edge walk per 16-lane group, unroll-4 MLP.
// ---------------------------------------------------------------------------

#define ACC_U(u)                                     \
    do {                                             \
        unsigned int ul_ = (unsigned int)(u);        \
        unsigned int uh_ = (unsigned int)((u) >> 32);\
        a0 += __uint_as_float(ul_ << 16);            \
        a1 += __uint_as_float(ul_ & 0xffff0000u);    \
        a2 += __uint_as_float(uh_ << 16);            \
        a3 += __uint_as_float(uh_ & 0xffff0000u);    \
    } while (0)

// Aggregate 1: act[chunk][node][64] = bf16(relu(dinv*sum(G1[src]) + b1)).
__global__ __launch_bounds__(256) void k_agg1(
    const int* __restrict__ row_ptr, const int* __restrict__ srcs,
    const ushort_t* __restrict__ G, const float* __restrict__ dinv,
    const float* __restrict__ bias, ull_t* __restrict__ ActOut,
    int n, int half) {
    int bx = blockIdx.x;
    int chunk = bx >= half ? 1 : 0;
    int tile = bx - chunk * half;
    int t = threadIdx.x;
    int lane = t & 63;
    int g = lane >> 4;     // node sub-index within wave (0..3)
    int q = lane & 15;     // 8 B quad within 64 channels
    int node = tile * 16 + (t >> 6) * 4 + g;
    bool valid = node < n;
    int nc = valid ? node : n - 1;
    int beg = row_ptr[nc], end = row_ptr[nc + 1];
    const ull_t* Tq = (const ull_t*)G + (size_t)chunk * n * 16 + q;
    float a0 = 0.f, a1 = 0.f, a2 = 0.f, a3 = 0.f;
    int e = beg;
    for (; e + 4 <= end; e += 4) {
        int s0 = srcs[e], s1 = srcs[e + 1], s2 = srcs[e + 2], s3 = srcs[e + 3];
        ull_t u0 = Tq[(size_t)s0 * 16];
        ull_t u1 = Tq[(size_t)s1 * 16];
        ull_t u2 = Tq[(size_t)s2 * 16];
        ull_t u3 = Tq[(size_t)s3 * 16];
        ACC_U(u0); ACC_U(u1); ACC_U(u2); ACC_U(u3);
    }
    for (; e < end; ++e) {
        int s = srcs[e];
        ull_t u = Tq[(size_t)s * 16];
        ACC_U(u);
    }
    if (valid) {
        float dv = dinv[node];
        const float* bp = bias + chunk * 64 + q * 4;
        a0 = fmaxf(fmaf(a0, dv, bp[0]), 0.f);
        a1 = fmaxf(fmaf(a1, dv, bp[1]), 0.f);
        a2 = fmaxf(fmaf(a2, dv, bp[2]), 0.f);
        a3 = fmaxf(fmaf(a3, dv, bp[3]), 0.f);
        unsigned int p0 = (unsigned int)f32_to_bf16_rne(a0) |
                          ((unsigned int)f32_to_bf16_rne(a1) << 16);
        unsigned int p1 = (unsigned int)f32_to_bf16_rne(a2) |
                          ((unsigned int)f32_to_bf16_rne(a3) << 16);
        ull_t uo = (ull_t)p0 | ((ull_t)p1 << 32);
        __builtin_nontemporal_store(uo, ActOut + ((size_t)chunk * n + node) * 16 + q);
    }
}

// Aggregate 2: out[node][chunk*64..] = dinv*sum(G2[src]) + b2 (f32, nt store).
__global__ __launch_bounds__(256) void k_agg2(
    const int* __restrict__ row_ptr, const int* __restrict__ srcs,
    const ushort_t* __restrict__ G, const float* __restrict__ dinv,
    const float* __restrict__ bias, float* __restrict__ Out,
    int n, int half) {
    int bx = blockIdx.x;
    int chunk = bx >= half ? 1 : 0;
    int tile = bx - chunk * half;
    int t = threadIdx.x;
    int lane = t & 63;
    int g = lane >> 4;
    int q = lane & 15;
    int node = tile * 16 + (t >> 6) * 4 + g;
    bool valid = node < n;
    int nc = valid ? node : n - 1;
    int beg = row_ptr[nc], end = row_ptr[nc + 1];
    const ull_t* Tq = (const ull_t*)G + (size_t)chunk * n * 16 + q;
    float a0 = 0.f, a1 = 0.f, a2 = 0.f, a3 = 0.f;
    int e = beg;
    for (; e + 4 <= end; e += 4) {
        int s0 = srcs[e], s1 = srcs[e + 1], s2 = srcs[e + 2], s3 = srcs[e + 3];
        ull_t u0 = Tq[(size_t)s0 * 16];
        ull_t u1 = Tq[(size_t)s1 * 16];
        ull_t u2 = Tq[(size_t)s2 * 16];
        ull_t u3 = Tq[(size_t)s3 * 16];
        ACC_U(u0); ACC_U(u1); ACC_U(u2); ACC_U(u3);
    }
    for (; e < end; ++e) {
        int s = srcs[e];
        ull_t u = Tq[(size_t)s * 16];
        ACC_U(u);
    }
    if (valid) {
        float dv = dinv[node];
        const float* bp = bias + chunk * 64 + q * 4;
        f32x4 o;
        o.x = fmaf(a0, dv, bp[0]);
        o.y = fmaf(a1, dv, bp[1]);
        o.z = fmaf(a2, dv, bp[2]);
        o.w = fmaf(a3, dv, bp[3]);
        __builtin_nontemporal_store(o,
            (f32x4*)(Out + (size_t)node * 128 + chunk * 64 + q * 4));
    }
}

extern "C" void kernel_launch(void* const* d_in, const int* in_sizes, int n_in,
                              void* d_out, int out_size, void* d_ws, size_t ws_size,
                              hipStream_t stream) {
    const float* x  = (const float*)d_in[0];
    const int*   ei = (const int*)d_in[1];
    const float* W1 = (const float*)d_in[2];
    const float* b1 = (const float*)d_in[3];
    const float* W2 = (const float*)d_in[4];
    const float* b2 = (const float*)d_in[5];
    float* out = (float*)d_out;

    const int C = 128;
    const int N = in_sizes[0] / C;
    const int E = in_sizes[1] / 2;
    const int* src = ei;
    const int* dst = ei + E;
    const int total = E + N;
    const int nbp = (N + NPB - 1) >> 7;                 // buckets (782)
    const int T = (total + PART_TILE - 1) / PART_TILE;  // tiles (202)

    char* ws = (char*)d_ws;
    size_t off = 0;
    auto alloc = [&](size_t bytes) -> void* {
        void* p = ws + off;
        off = (off + bytes + 511) & ~(size_t)511;
        return p;
    };
    int*   cnt        = (int*)alloc((size_t)nbp * 4);
    int*   bucket_ptr = (int*)alloc((size_t)(nbp + 1) * 4);
    int*   row_ptr    = (int*)alloc(((size_t)N + 1) * 4);
    float* dinv       = (float*)alloc((size_t)N * 4);
    int*   srcs       = (int*)alloc((size_t)total * 4);
    ushort_t* Wp1     = (ushort_t*)alloc(128 * 128 * 2);
    ushort_t* Wp2     = (ushort_t*)alloc(128 * 128 * 2);
    ushort_t* G1      = (ushort_t*)alloc((size_t)N * C * 2);
    // act/G2 (in-place, N*C*2 = 25.6 MB) shares with pairs (nbp*CAP*4 =
    // 16 MB): pairs dead after k_build, act written by k_agg1 afterwards.
    size_t ab = (size_t)N * C * 2, pb = (size_t)nbp * CAP * 4;
    void* shared = alloc(ab > pb ? ab : pb);
    ushort_t* actG2 = (ushort_t*)shared;
    unsigned int* pairs = (unsigned int*)shared;

    // ---- CSR build: dynamic two-phase partition -> scan -> build ----
    hipMemsetAsync(cnt, 0, (size_t)nbp * 4, stream);
    k_part2<<<T, 256, 0, stream>>>(src, dst, cnt, pairs, E, nbp, total);
    k_bscan<<<129, 256, 0, stream>>>(cnt, bucket_ptr, nbp, total,
                                     W1, W2, Wp1, Wp2);
    k_build<<<nbp, 256, 0, stream>>>(pairs, cnt, bucket_ptr,
                                     row_ptr, srcs, dinv, N);

    // agg grid: two sequential halves (chunk = bx >= half), 16 nodes/block
    const int half = (N + 15) / 16;
    dim3 agrid(half * 2);

    // ---- layer 1: G1[ch][r][64] = bf16(dinv*(x@W1)); act chunked bf16 ----
    k_gemm1<<<(N + 63) / 64, 256, 0, stream>>>(x, Wp1, dinv, G1, N);
    k_agg1<<<agrid, 256, 0, stream>>>(row_ptr, srcs, G1, dinv, b1,
                                      (ull_t*)actG2, N, half);

    // ---- layer 2: G2 = bf16(dinv*(act@W2)) in-place chunked; out ----
    k_gemm2<<<(N + 63) / 64, 256, 0, stream>>>(actG2, Wp2, dinv, N);
    k_agg2<<<agrid, 256, 0, stream>>>(row_ptr, srcs, actG2, dinv, b2, out, N, half);
}